// Round 7
// baseline (1066.724 us; speedup 1.0000x reference)
//
#include <hip/hip_runtime.h>

#define NN 50000
#define NE 1600000
#define FIN 128
#define FOUT 64
#define ALPHA 0.2f
#define NPB 64                      // nodes per bucket
#define NB  782                     // ceil(NN/NPB)

// ---------- int width sniffer: int32 (0) vs int64 (1) ----------
__global__ void k_sniff(const int* __restrict__ edge32, int* __restrict__ iflag) {
    __shared__ int zodd;
    if (threadIdx.x == 0) zodd = 0;
    __syncthreads();
    int z = 0;
    for (int i = threadIdx.x; i < 2048; i += 256)
        if (edge32[2 * i + 1] == 0) z++;
    atomicAdd(&zodd, z);
    __syncthreads();
    if (threadIdx.x == 0) *iflag = (zodd > 2000) ? 1 : 0;
}

__device__ inline int ldi(const void* p, size_t i, int isi64) {
    int v = isi64 ? (int)((const long long*)p)[i] : ((const int*)p)[i];
    return v < 0 ? 0 : (v >= NN ? NN - 1 : v);
}

// ---------- K0: u = W @ {a1l,a1r,a2l,a2r} ----------
__global__ void k_u(const float* __restrict__ W, const float* __restrict__ a1,
                    const float* __restrict__ a2, float* __restrict__ u) {
    int k = threadIdx.x;
    float u1 = 0.f, u2 = 0.f, u3 = 0.f, u4 = 0.f;
    for (int j = 0; j < FOUT; j++) {
        float w = W[k * FOUT + j];
        u1 += w * a1[j];
        u2 += w * a1[FOUT + j];
        u3 += w * a2[j];
        u4 += w * a2[FOUT + j];
    }
    u[k] = u1; u[128 + k] = u2; u[256 + k] = u3; u[384 + k] = u4;
}

// ---------- K1: h = input @ W (x via LDS float4 broadcast) ----------
__global__ __launch_bounds__(256) void k_gemm(const float* __restrict__ X,
                                              const float* __restrict__ W,
                                              float* __restrict__ h) {
    __shared__ float wlds[FIN * FOUT];      // 32 KB
    __shared__ float xlds[4][4][FIN];       // 8 KB
    int tid = threadIdx.x;
    for (int i = tid; i < FIN * FOUT; i += 256) wlds[i] = W[i];
    int wave = tid >> 6, lane = tid & 63;
    int base = blockIdx.x * 16 + wave * 4;  // 3125*16 = 50000
    for (int n0 = 0; n0 < 4; n0++) {
        float2 b = ((const float2*)(X + (size_t)(base + n0) * FIN))[lane];
        xlds[wave][n0][2 * lane] = b.x;
        xlds[wave][n0][2 * lane + 1] = b.y;
    }
    __syncthreads();
    float a0 = 0.f, a1v = 0.f, a2v = 0.f, a3 = 0.f;
#pragma unroll 4
    for (int k = 0; k < FIN; k += 4) {
        float4 x0 = *(const float4*)&xlds[wave][0][k];   // same-addr broadcast: free
        float4 x1 = *(const float4*)&xlds[wave][1][k];
        float4 x2 = *(const float4*)&xlds[wave][2][k];
        float4 x3 = *(const float4*)&xlds[wave][3][k];
        float w0 = wlds[(k + 0) * FOUT + lane];
        float w1 = wlds[(k + 1) * FOUT + lane];
        float w2 = wlds[(k + 2) * FOUT + lane];
        float w3 = wlds[(k + 3) * FOUT + lane];
        a0  += x0.x * w0 + x0.y * w1 + x0.z * w2 + x0.w * w3;
        a1v += x1.x * w0 + x1.y * w1 + x1.z * w2 + x1.w * w3;
        a2v += x2.x * w0 + x2.y * w1 + x2.z * w2 + x2.w * w3;
        a3  += x3.x * w0 + x3.y * w1 + x3.z * w2 + x3.w * w3;
    }
    h[(size_t)(base + 0) * FOUT + lane] = a0;
    h[(size_t)(base + 1) * FOUT + lane] = a1v;
    h[(size_t)(base + 2) * FOUT + lane] = a2v;
    h[(size_t)(base + 3) * FOUT + lane] = a3;
}

// ---------- K1b: per-node score scalars ----------
__global__ __launch_bounds__(256) void k_svec(const float* __restrict__ input,
                                              const float* __restrict__ p_h,
                                              const float* __restrict__ new_h,
                                              const float* __restrict__ u,
                                              float* __restrict__ s1, float* __restrict__ s2,
                                              float* __restrict__ s3, float* __restrict__ s4) {
    int lane = threadIdx.x & 63;
    int v = blockIdx.x * 4 + (threadIdx.x >> 6);
    size_t row = (size_t)v * FIN;
    float2 bi = ((const float2*)(input + row))[lane];
    float2 bp = ((const float2*)(p_h   + row))[lane];
    float2 bn = ((const float2*)(new_h + row))[lane];
    float p1 = bi.x * u[2 * lane]       + bi.y * u[2 * lane + 1];
    float p2 = bp.x * u[128 + 2 * lane] + bp.y * u[128 + 2 * lane + 1];
    float p3 = bn.x * u[256 + 2 * lane] + bn.y * u[256 + 2 * lane + 1];
    float p4 = bi.x * u[384 + 2 * lane] + bi.y * u[384 + 2 * lane + 1];
#pragma unroll
    for (int off = 32; off > 0; off >>= 1) {
        p1 += __shfl_down(p1, off, 64);
        p2 += __shfl_down(p2, off, 64);
        p3 += __shfl_down(p3, off, 64);
        p4 += __shfl_down(p4, off, 64);
    }
    if (lane == 0) { s1[v] = p1; s2[v] = p2; s3[v] = p3; s4[v] = p4; }
}

// ---------- K2..K4: column softmax ----------
__global__ void k_colscore(const float* __restrict__ s1, const float* __restrict__ s2,
                           const void* __restrict__ edge_col, const void* __restrict__ row_i,
                           const int* __restrict__ iflag,
                           float* __restrict__ ec, unsigned int* __restrict__ m) {
    int i = blockIdx.x * 256 + threadIdx.x;
    if (i >= NN) return;
    int i64 = *iflag;
    float cs = s1[ldi(edge_col, i, i64)] + s2[i];
    float l = cs > 0.f ? cs : ALPHA * cs;
    float e = expf(-l);
    ec[i] = e;
    atomicMax(&m[ldi(row_i, i, i64)], __float_as_uint(e));
}

__global__ void k_expsum(float* __restrict__ ec, const unsigned int* __restrict__ m,
                         const void* __restrict__ row_i, const int* __restrict__ iflag,
                         float* __restrict__ ssum) {
    int i = blockIdx.x * 256 + threadIdx.x;
    if (i >= NN) return;
    int r = ldi(row_i, i, *iflag);
    float e = expf(ec[i] - __uint_as_float(m[r]));
    ec[i] = e;
    atomicAdd(&ssum[r], e);
}

__global__ void k_norm(const float* __restrict__ ex, const float* __restrict__ ssum,
                       const void* __restrict__ row_i, const int* __restrict__ iflag,
                       float* __restrict__ ecs) {
    int i = blockIdx.x * 256 + threadIdx.x;
    if (i >= NN) return;
    ecs[i] = ex[i] / (ssum[ldi(row_i, i, *iflag)] + 1e-16f);
}

// ---------- K5a: coarse bucket histogram (cursors padded to 64B lines) ----------
__global__ void k_bhist(const void* __restrict__ edge, const int* __restrict__ iflag,
                        int* __restrict__ bhist_p) {
    int e = blockIdx.x * 256 + threadIdx.x;           // NE/256 blocks
    int b = ldi(edge, e, *iflag) >> 6;                // e0 / NPB
    atomicAdd(&bhist_p[b * 16], 1);
}

// ---------- K5b: one-block scan of 782 buckets ----------
__global__ __launch_bounds__(1024) void k_bscan(const int* __restrict__ bhist_p,
                                                int* __restrict__ bstart, int* __restrict__ bcur_p) {
    __shared__ int s[1024];
    int tid = threadIdx.x;
    int x = (tid < NB) ? bhist_p[tid * 16] : 0;
    s[tid] = x;
    __syncthreads();
    for (int off = 1; off < 1024; off <<= 1) {
        int t = (tid >= off) ? s[tid - off] : 0;
        __syncthreads();
        s[tid] += t;
        __syncthreads();
    }
    int excl = s[tid] - x;
    if (tid < NB) { bstart[tid] = excl; bcur_p[tid * 16] = excl; }
    if (tid == NB - 1) bstart[NB] = excl + x;         // == NE
}

// ---------- K5c: per-edge score + bucket-append packed record ----------
// record: .x = int bits (node_local<<16 | e1), .y = ee
__global__ __launch_bounds__(256) void k_edge2(const float* __restrict__ s3, const float* __restrict__ s4,
                                               const float* __restrict__ ecs,
                                               const void* __restrict__ edge, const void* __restrict__ row_resort,
                                               const int* __restrict__ iflag,
                                               int* __restrict__ bcur_p, float2* __restrict__ recs,
                                               float* __restrict__ edge_e /* = out2 */) {
    int e = blockIdx.x * 256 + threadIdx.x;
    int i64 = *iflag;
    int e0 = ldi(edge, e, i64);
    int e1 = ldi(edge, (size_t)NE + e, i64);
    int rr = ldi(row_resort, e, i64);
    float rs = s3[rr] + s4[e1];
    float l = rs > 0.f ? rs : ALPHA * rs;
    float ee = expf(-l) * ecs[rr];
    edge_e[e] = ee;
    int b = e0 >> 6;
    int pos = atomicAdd(&bcur_p[b * 16], 1);
    recs[pos] = make_float2(__int_as_float(((e0 & 63) << 16) | e1), ee);
}

// ---------- K6: per-bucket LDS aggregation; fused rowsum/divide/elu ----------
__global__ __launch_bounds__(256) void k_agg2(const float* __restrict__ h,
                                              const float2* __restrict__ recs,
                                              const int* __restrict__ bstart,
                                              float* __restrict__ ersum,
                                              float* __restrict__ out0) {
    __shared__ float acc[NPB][FOUT];    // 16 KB; stride 64 -> 2-way bank alias (free)
    __shared__ float rsum[NPB];
    int tid = threadIdx.x, wave = tid >> 6, lane = tid & 63;
    for (int i = tid; i < NPB * FOUT; i += 256) ((float*)acc)[i] = 0.f;
    if (tid < NPB) rsum[tid] = 0.f;
    __syncthreads();
    int b = blockIdx.x;
    int a = bstart[b], e = bstart[b + 1];
    int j = a + wave * 4;
    for (; j + 4 <= e; j += 16) {
        float2 p0 = recs[j + 0], p1 = recs[j + 1], p2 = recs[j + 2], p3 = recs[j + 3];
        int k0 = __float_as_int(p0.x), k1 = __float_as_int(p1.x),
            k2 = __float_as_int(p2.x), k3 = __float_as_int(p3.x);
        float h0 = h[(size_t)(k0 & 0xFFFF) * FOUT + lane];
        float h1 = h[(size_t)(k1 & 0xFFFF) * FOUT + lane];
        float h2 = h[(size_t)(k2 & 0xFFFF) * FOUT + lane];
        float h3 = h[(size_t)(k3 & 0xFFFF) * FOUT + lane];
        atomicAdd(&acc[k0 >> 16][lane], p0.y * h0);
        atomicAdd(&acc[k1 >> 16][lane], p1.y * h1);
        atomicAdd(&acc[k2 >> 16][lane], p2.y * h2);
        atomicAdd(&acc[k3 >> 16][lane], p3.y * h3);
        if (lane == 0) {
            atomicAdd(&rsum[k0 >> 16], p0.y);
            atomicAdd(&rsum[k1 >> 16], p1.y);
            atomicAdd(&rsum[k2 >> 16], p2.y);
            atomicAdd(&rsum[k3 >> 16], p3.y);
        }
    }
    for (int t = j; t < e && t < j + 4; t++) {        // per-wave tail (<4 recs)
        float2 p = recs[t];
        int k = __float_as_int(p.x);
        float hv = h[(size_t)(k & 0xFFFF) * FOUT + lane];
        atomicAdd(&acc[k >> 16][lane], p.y * hv);
        if (lane == 0) atomicAdd(&rsum[k >> 16], p.y);
    }
    __syncthreads();
    for (int n = wave; n < NPB; n += 4) {
        int v = b * NPB + n;
        if (v >= NN) continue;
        float rs = rsum[n];
        rs += (rs == 0.f) ? 1.f : 0.f;
        float hp = acc[n][lane] / rs;
        out0[(size_t)v * FOUT + lane] = hp > 0.f ? hp : expm1f(hp);
        if (lane == 0) ersum[v] = rs;
    }
}

// ---------- K7: out2 = numerator / rowsum, in place ----------
__global__ void k_att(const void* __restrict__ edge, const int* __restrict__ iflag,
                      const float* __restrict__ ersum, float* __restrict__ out2) {
    int e = blockIdx.x * 256 + threadIdx.x;
    out2[e] = out2[e] / ersum[ldi(edge, e, *iflag)];
}

// ---------- K8: out1 = float(edge), runs LAST (overwrites recs region) ----------
__global__ void k_edgecopy(const void* __restrict__ edge, const int* __restrict__ iflag,
                           float* __restrict__ out1) {
    int i = blockIdx.x * 256 + threadIdx.x;
    int i64 = *iflag;
    int v = i64 ? (int)((const long long*)edge)[i] : ((const int*)edge)[i];
    out1[i] = (float)v;
}

extern "C" void kernel_launch(void* const* d_in, const int* in_sizes, int n_in,
                              void* d_out, int out_size, void* d_ws, size_t ws_size,
                              hipStream_t stream) {
    int ix[3] = {0, 1, 2}; int nx = 0;
    int iE = 3, iCol = 4, iRowI = 5, iRes = 6, iW = 8, iA1 = 9, iA2 = 10;
    bool a1seen = false;
    for (int i = 0; i < n_in; i++) {
        int s = in_sizes[i];
        if (s == NN * FIN) { if (nx < 3) ix[nx++] = i; }
        else if (s == 2 * NE) iE = i;
        else if (s == 2 * NN) iCol = i;
        else if (s == NN) iRowI = i;
        else if (s == NE) iRes = i;
        else if (s == FIN * FOUT) iW = i;
        else if (s == 2 * FOUT) { if (!a1seen) { iA1 = i; a1seen = true; } else iA2 = i; }
    }
    const float* input = (const float*)d_in[ix[0]];
    const float* p_h   = (const float*)d_in[ix[1]];
    const float* new_h = (const float*)d_in[ix[2]];
    const void* edge       = d_in[iE];
    const void* edge_col   = d_in[iCol];
    const void* row_i      = d_in[iRowI];
    const void* row_resort = d_in[iRes];
    const float* W  = (const float*)d_in[iW];
    const float* a1 = (const float*)d_in[iA1];
    const float* a2 = (const float*)d_in[iA2];

    float* out0 = (float*)d_out;                      // N*FOUT
    float* out1 = out0 + (size_t)NN * FOUT;           // 2*NE (recs scratch until k_edgecopy)
    float* out2 = out1 + (size_t)2 * NE;              // NE

    float2* recs = (float2*)out1;                     // NE x 8B fits exactly

    // ws (~14.5 MB)
    float* h     = (float*)d_ws;                      // NN*FOUT
    float* s1    = h + (size_t)NN * FOUT;
    float* s2    = s1 + NN;
    float* s3    = s2 + NN;
    float* s4    = s3 + NN;
    float* ec    = s4 + NN;                           // reused as ex
    float* ecs   = ec + NN;
    float* mseg  = ecs + NN;                          // zeroed
    float* ssum  = mseg + NN;                         // zeroed
    int*   bhist_p = (int*)(ssum + NN);               // NB*16, zeroed
    int*   bstart  = bhist_p + NB * 16;               // NB+1
    int*   bcur_p  = bstart + NB + 1;                 // NB*16
    float* ersum   = (float*)(bcur_p + NB * 16);      // NN
    float* u       = ersum + NN;                      // 512
    int*   iflag   = (int*)(u + 512);

    hipMemsetAsync(mseg, 0, ((size_t)2 * NN + NB * 16) * sizeof(float), stream); // mseg, ssum, bhist_p

    k_sniff<<<1, 256, 0, stream>>>((const int*)edge, iflag);
    k_u<<<1, 128, 0, stream>>>(W, a1, a2, u);
    k_gemm<<<NN / 16, 256, 0, stream>>>(input, W, h);
    k_svec<<<NN / 4, 256, 0, stream>>>(input, p_h, new_h, u, s1, s2, s3, s4);
    k_colscore<<<(NN + 255) / 256, 256, 0, stream>>>(s1, s2, edge_col, row_i, iflag, ec, (unsigned int*)mseg);
    k_expsum<<<(NN + 255) / 256, 256, 0, stream>>>(ec, (const unsigned int*)mseg, row_i, iflag, ssum);
    k_norm<<<(NN + 255) / 256, 256, 0, stream>>>(ec, ssum, row_i, iflag, ecs);
    k_bhist<<<NE / 256, 256, 0, stream>>>(edge, iflag, bhist_p);
    k_bscan<<<1, 1024, 0, stream>>>(bhist_p, bstart, bcur_p);
    k_edge2<<<NE / 256, 256, 0, stream>>>(s3, s4, ecs, edge, row_resort, iflag, bcur_p, recs, out2);
    k_agg2<<<NB, 256, 0, stream>>>(h, recs, bstart, ersum, out0);
    k_att<<<NE / 256, 256, 0, stream>>>(edge, iflag, ersum, out2);
    k_edgecopy<<<2 * NE / 256, 256, 0, stream>>>(edge, iflag, out1);
}

// Round 8
// 471.516 us; speedup vs baseline: 2.2623x; 2.2623x over previous
//
#include <hip/hip_runtime.h>

#define NN 50000
#define NE 1600000
#define FIN 128
#define FOUT 64
#define ALPHA 0.2f
#define NPB 64                      // nodes per bucket
#define NB  782                     // ceil(NN/NPB)
#define CAP 2560                    // records per LDS chunk (mean 2046, +11 sigma)

// ---------- int width sniffer: int32 (0) vs int64 (1) ----------
__global__ void k_sniff(const int* __restrict__ edge32, int* __restrict__ iflag) {
    __shared__ int zodd;
    if (threadIdx.x == 0) zodd = 0;
    __syncthreads();
    int z = 0;
    for (int i = threadIdx.x; i < 2048; i += 256)
        if (edge32[2 * i + 1] == 0) z++;
    atomicAdd(&zodd, z);
    __syncthreads();
    if (threadIdx.x == 0) *iflag = (zodd > 2000) ? 1 : 0;
}

__device__ inline int ldi(const void* p, size_t i, int isi64) {
    int v = isi64 ? (int)((const long long*)p)[i] : ((const int*)p)[i];
    return v < 0 ? 0 : (v >= NN ? NN - 1 : v);
}

// ---------- K0: u = W @ {a1l,a1r,a2l,a2r} ----------
__global__ void k_u(const float* __restrict__ W, const float* __restrict__ a1,
                    const float* __restrict__ a2, float* __restrict__ u) {
    int k = threadIdx.x;
    float u1 = 0.f, u2 = 0.f, u3 = 0.f, u4 = 0.f;
    for (int j = 0; j < FOUT; j++) {
        float w = W[k * FOUT + j];
        u1 += w * a1[j];
        u2 += w * a1[FOUT + j];
        u3 += w * a2[j];
        u4 += w * a2[FOUT + j];
    }
    u[k] = u1; u[128 + k] = u2; u[256 + k] = u3; u[384 + k] = u4;
}

// ---------- K1: h = input @ W (x via LDS float4 broadcast) ----------
__global__ __launch_bounds__(256) void k_gemm(const float* __restrict__ X,
                                              const float* __restrict__ W,
                                              float* __restrict__ h) {
    __shared__ float wlds[FIN * FOUT];      // 32 KB
    __shared__ float xlds[4][4][FIN];       // 8 KB
    int tid = threadIdx.x;
    for (int i = tid; i < FIN * FOUT; i += 256) wlds[i] = W[i];
    int wave = tid >> 6, lane = tid & 63;
    int base = blockIdx.x * 16 + wave * 4;  // 3125*16 = 50000
    for (int n0 = 0; n0 < 4; n0++) {
        float2 b = ((const float2*)(X + (size_t)(base + n0) * FIN))[lane];
        xlds[wave][n0][2 * lane] = b.x;
        xlds[wave][n0][2 * lane + 1] = b.y;
    }
    __syncthreads();
    float a0 = 0.f, a1v = 0.f, a2v = 0.f, a3 = 0.f;
#pragma unroll 4
    for (int k = 0; k < FIN; k += 4) {
        float4 x0 = *(const float4*)&xlds[wave][0][k];   // same-addr broadcast: free
        float4 x1 = *(const float4*)&xlds[wave][1][k];
        float4 x2 = *(const float4*)&xlds[wave][2][k];
        float4 x3 = *(const float4*)&xlds[wave][3][k];
        float w0 = wlds[(k + 0) * FOUT + lane];
        float w1 = wlds[(k + 1) * FOUT + lane];
        float w2 = wlds[(k + 2) * FOUT + lane];
        float w3 = wlds[(k + 3) * FOUT + lane];
        a0  += x0.x * w0 + x0.y * w1 + x0.z * w2 + x0.w * w3;
        a1v += x1.x * w0 + x1.y * w1 + x1.z * w2 + x1.w * w3;
        a2v += x2.x * w0 + x2.y * w1 + x2.z * w2 + x2.w * w3;
        a3  += x3.x * w0 + x3.y * w1 + x3.z * w2 + x3.w * w3;
    }
    h[(size_t)(base + 0) * FOUT + lane] = a0;
    h[(size_t)(base + 1) * FOUT + lane] = a1v;
    h[(size_t)(base + 2) * FOUT + lane] = a2v;
    h[(size_t)(base + 3) * FOUT + lane] = a3;
}

// ---------- K1b: per-node score scalars ----------
__global__ __launch_bounds__(256) void k_svec(const float* __restrict__ input,
                                              const float* __restrict__ p_h,
                                              const float* __restrict__ new_h,
                                              const float* __restrict__ u,
                                              float* __restrict__ s1, float* __restrict__ s2,
                                              float* __restrict__ s3, float* __restrict__ s4) {
    int lane = threadIdx.x & 63;
    int v = blockIdx.x * 4 + (threadIdx.x >> 6);
    size_t row = (size_t)v * FIN;
    float2 bi = ((const float2*)(input + row))[lane];
    float2 bp = ((const float2*)(p_h   + row))[lane];
    float2 bn = ((const float2*)(new_h + row))[lane];
    float p1 = bi.x * u[2 * lane]       + bi.y * u[2 * lane + 1];
    float p2 = bp.x * u[128 + 2 * lane] + bp.y * u[128 + 2 * lane + 1];
    float p3 = bn.x * u[256 + 2 * lane] + bn.y * u[256 + 2 * lane + 1];
    float p4 = bi.x * u[384 + 2 * lane] + bi.y * u[384 + 2 * lane + 1];
#pragma unroll
    for (int off = 32; off > 0; off >>= 1) {
        p1 += __shfl_down(p1, off, 64);
        p2 += __shfl_down(p2, off, 64);
        p3 += __shfl_down(p3, off, 64);
        p4 += __shfl_down(p4, off, 64);
    }
    if (lane == 0) { s1[v] = p1; s2[v] = p2; s3[v] = p3; s4[v] = p4; }
}

// ---------- K2..K4: column softmax ----------
__global__ void k_colscore(const float* __restrict__ s1, const float* __restrict__ s2,
                           const void* __restrict__ edge_col, const void* __restrict__ row_i,
                           const int* __restrict__ iflag,
                           float* __restrict__ ec, unsigned int* __restrict__ m) {
    int i = blockIdx.x * 256 + threadIdx.x;
    if (i >= NN) return;
    int i64 = *iflag;
    float cs = s1[ldi(edge_col, i, i64)] + s2[i];
    float l = cs > 0.f ? cs : ALPHA * cs;
    float e = expf(-l);
    ec[i] = e;
    atomicMax(&m[ldi(row_i, i, i64)], __float_as_uint(e));
}

__global__ void k_expsum(float* __restrict__ ec, const unsigned int* __restrict__ m,
                         const void* __restrict__ row_i, const int* __restrict__ iflag,
                         float* __restrict__ ssum) {
    int i = blockIdx.x * 256 + threadIdx.x;
    if (i >= NN) return;
    int r = ldi(row_i, i, *iflag);
    float e = expf(ec[i] - __uint_as_float(m[r]));
    ec[i] = e;
    atomicAdd(&ssum[r], e);
}

__global__ void k_norm(const float* __restrict__ ex, const float* __restrict__ ssum,
                       const void* __restrict__ row_i, const int* __restrict__ iflag,
                       float* __restrict__ ecs) {
    int i = blockIdx.x * 256 + threadIdx.x;
    if (i >= NN) return;
    ecs[i] = ex[i] / (ssum[ldi(row_i, i, *iflag)] + 1e-16f);
}

// ---------- K5a: coarse bucket histogram (cursors padded to 64B lines) ----------
__global__ void k_bhist(const void* __restrict__ edge, const int* __restrict__ iflag,
                        int* __restrict__ bhist_p) {
    int e = blockIdx.x * 256 + threadIdx.x;
    int b = ldi(edge, e, *iflag) >> 6;
    atomicAdd(&bhist_p[b * 16], 1);
}

// ---------- K5b: one-block scan of 782 buckets ----------
__global__ __launch_bounds__(1024) void k_bscan(const int* __restrict__ bhist_p,
                                                int* __restrict__ bstart, int* __restrict__ bcur_p) {
    __shared__ int s[1024];
    int tid = threadIdx.x;
    int x = (tid < NB) ? bhist_p[tid * 16] : 0;
    s[tid] = x;
    __syncthreads();
    for (int off = 1; off < 1024; off <<= 1) {
        int t = (tid >= off) ? s[tid - off] : 0;
        __syncthreads();
        s[tid] += t;
        __syncthreads();
    }
    int excl = s[tid] - x;
    if (tid < NB) { bstart[tid] = excl; bcur_p[tid * 16] = excl; }
    if (tid == NB - 1) bstart[NB] = excl + x;         // == NE
}

// ---------- K5c: per-edge score + bucket-append packed record ----------
// record: .x = int bits (node_local<<16 | e1), .y = ee
__global__ __launch_bounds__(256) void k_edge2(const float* __restrict__ s3, const float* __restrict__ s4,
                                               const float* __restrict__ ecs,
                                               const void* __restrict__ edge, const void* __restrict__ row_resort,
                                               const int* __restrict__ iflag,
                                               int* __restrict__ bcur_p, float2* __restrict__ recs,
                                               float* __restrict__ edge_e /* = out2 */) {
    int e = blockIdx.x * 256 + threadIdx.x;
    int i64 = *iflag;
    int e0 = ldi(edge, e, i64);
    int e1 = ldi(edge, (size_t)NE + e, i64);
    int rr = ldi(row_resort, e, i64);
    float rs = s3[rr] + s4[e1];
    float l = rs > 0.f ? rs : ALPHA * rs;
    float ee = expf(-l) * ecs[rr];
    edge_e[e] = ee;
    int b = e0 >> 6;
    int pos = atomicAdd(&bcur_p[b * 16], 1);
    recs[pos] = make_float2(__int_as_float(((e0 & 63) << 16) | e1), ee);
}

// ---------- K6: per-bucket counting-sort + register-accumulated gather ----------
// One block per bucket. Counting sort in LDS (2 int atomics/record), then each
// wave owns nodes n = 4t+wave (t unrolled -> register accumulators), gathers h
// rows for its runs, fused rowsum/divide/elu. Zero global atomics.
__global__ __launch_bounds__(256) void k_agg3(const float* __restrict__ h,
                                              const float2* __restrict__ recs,
                                              const int* __restrict__ bstart,
                                              float* __restrict__ ersum,
                                              float* __restrict__ out0) {
    __shared__ float2 lrec[CAP];            // 20 KB
    __shared__ unsigned short sidx[CAP];    // 5 KB
    __shared__ int cnt[NPB], off[NPB], cur[NPB];
    int tid = threadIdx.x, wave = tid >> 6, lane = tid & 63;
    int b = blockIdx.x;
    int a = bstart[b], e = bstart[b + 1];
    float accv[16], rsv[16];
#pragma unroll
    for (int t = 0; t < 16; t++) { accv[t] = 0.f; rsv[t] = 0.f; }

    for (int base = a; base < e; base += CAP) {       // single iteration in practice
        int m = e - base; if (m > CAP) m = CAP;
        if (tid < NPB) cnt[tid] = 0;
        __syncthreads();
        for (int i = tid; i < m; i += 256) {          // coalesced load + count
            float2 p = recs[base + i];
            lrec[i] = p;
            atomicAdd(&cnt[__float_as_int(p.x) >> 16], 1);
        }
        __syncthreads();
        if (tid < NPB) {                              // wave 0: exclusive scan of 64
            int x = cnt[tid];
            int s = x;
#pragma unroll
            for (int o = 1; o < 64; o <<= 1) {
                int t = __shfl_up(s, o, 64);
                if (tid >= o) s += t;
            }
            off[tid] = s - x;
            cur[tid] = s - x;
        }
        __syncthreads();
        for (int i = tid; i < m; i += 256) {          // counting scatter of indices
            int n = __float_as_int(lrec[i].x) >> 16;
            int pos = atomicAdd(&cur[n], 1);
            sidx[pos] = (unsigned short)i;
        }
        __syncthreads();
#pragma unroll
        for (int t = 0; t < 16; t++) {                // 16 nodes per wave, static regs
            int n = 4 * t + wave;
            int s0 = off[n], c = cnt[n];
            float la = 0.f, lr = 0.f;
            int j = s0;
            for (; j + 4 <= s0 + c; j += 4) {         // 4 outstanding h-row gathers
                int i0 = sidx[j], i1 = sidx[j + 1], i2 = sidx[j + 2], i3 = sidx[j + 3];
                float2 p0 = lrec[i0], p1 = lrec[i1], p2 = lrec[i2], p3 = lrec[i3];
                float h0 = h[(size_t)(__float_as_int(p0.x) & 0xFFFF) * FOUT + lane];
                float h1 = h[(size_t)(__float_as_int(p1.x) & 0xFFFF) * FOUT + lane];
                float h2 = h[(size_t)(__float_as_int(p2.x) & 0xFFFF) * FOUT + lane];
                float h3 = h[(size_t)(__float_as_int(p3.x) & 0xFFFF) * FOUT + lane];
                lr += (p0.y + p1.y) + (p2.y + p3.y);
                la += p0.y * h0 + p1.y * h1 + p2.y * h2 + p3.y * h3;
            }
            for (; j < s0 + c; j++) {
                float2 p = lrec[sidx[j]];
                lr += p.y;
                la += p.y * h[(size_t)(__float_as_int(p.x) & 0xFFFF) * FOUT + lane];
            }
            accv[t] += la; rsv[t] += lr;
        }
        __syncthreads();                              // protect lrec before next chunk
    }
#pragma unroll
    for (int t = 0; t < 16; t++) {
        int v = b * NPB + 4 * t + wave;
        if (v < NN) {
            float rs = rsv[t];
            rs += (rs == 0.f) ? 1.f : 0.f;
            float hp = accv[t] / rs;
            out0[(size_t)v * FOUT + lane] = hp > 0.f ? hp : expm1f(hp);
            if (lane == 0) ersum[v] = rs;
        }
    }
}

// ---------- K7: out2 = numerator / rowsum, in place ----------
__global__ void k_att(const void* __restrict__ edge, const int* __restrict__ iflag,
                      const float* __restrict__ ersum, float* __restrict__ out2) {
    int e = blockIdx.x * 256 + threadIdx.x;
    out2[e] = out2[e] / ersum[ldi(edge, e, *iflag)];
}

// ---------- K8: out1 = float(edge), runs LAST (overwrites recs region) ----------
__global__ void k_edgecopy(const void* __restrict__ edge, const int* __restrict__ iflag,
                           float* __restrict__ out1) {
    int i = blockIdx.x * 256 + threadIdx.x;
    int i64 = *iflag;
    int v = i64 ? (int)((const long long*)edge)[i] : ((const int*)edge)[i];
    out1[i] = (float)v;
}

extern "C" void kernel_launch(void* const* d_in, const int* in_sizes, int n_in,
                              void* d_out, int out_size, void* d_ws, size_t ws_size,
                              hipStream_t stream) {
    int ix[3] = {0, 1, 2}; int nx = 0;
    int iE = 3, iCol = 4, iRowI = 5, iRes = 6, iW = 8, iA1 = 9, iA2 = 10;
    bool a1seen = false;
    for (int i = 0; i < n_in; i++) {
        int s = in_sizes[i];
        if (s == NN * FIN) { if (nx < 3) ix[nx++] = i; }
        else if (s == 2 * NE) iE = i;
        else if (s == 2 * NN) iCol = i;
        else if (s == NN) iRowI = i;
        else if (s == NE) iRes = i;
        else if (s == FIN * FOUT) iW = i;
        else if (s == 2 * FOUT) { if (!a1seen) { iA1 = i; a1seen = true; } else iA2 = i; }
    }
    const float* input = (const float*)d_in[ix[0]];
    const float* p_h   = (const float*)d_in[ix[1]];
    const float* new_h = (const float*)d_in[ix[2]];
    const void* edge       = d_in[iE];
    const void* edge_col   = d_in[iCol];
    const void* row_i      = d_in[iRowI];
    const void* row_resort = d_in[iRes];
    const float* W  = (const float*)d_in[iW];
    const float* a1 = (const float*)d_in[iA1];
    const float* a2 = (const float*)d_in[iA2];

    float* out0 = (float*)d_out;                      // N*FOUT
    float* out1 = out0 + (size_t)NN * FOUT;           // 2*NE (recs scratch until k_edgecopy)
    float* out2 = out1 + (size_t)2 * NE;              // NE

    float2* recs = (float2*)out1;                     // NE x 8B fits exactly

    // ws (~14.5 MB)
    float* h     = (float*)d_ws;                      // NN*FOUT
    float* s1    = h + (size_t)NN * FOUT;
    float* s2    = s1 + NN;
    float* s3    = s2 + NN;
    float* s4    = s3 + NN;
    float* ec    = s4 + NN;                           // reused as ex
    float* ecs   = ec + NN;
    float* mseg  = ecs + NN;                          // zeroed
    float* ssum  = mseg + NN;                         // zeroed
    int*   bhist_p = (int*)(ssum + NN);               // NB*16, zeroed
    int*   bstart  = bhist_p + NB * 16;               // NB+1
    int*   bcur_p  = bstart + NB + 1;                 // NB*16
    float* ersum   = (float*)(bcur_p + NB * 16);      // NN
    float* u       = ersum + NN;                      // 512
    int*   iflag   = (int*)(u + 512);

    hipMemsetAsync(mseg, 0, ((size_t)2 * NN + NB * 16) * sizeof(float), stream); // mseg, ssum, bhist_p

    k_sniff<<<1, 256, 0, stream>>>((const int*)edge, iflag);
    k_u<<<1, 128, 0, stream>>>(W, a1, a2, u);
    k_gemm<<<NN / 16, 256, 0, stream>>>(input, W, h);
    k_svec<<<NN / 4, 256, 0, stream>>>(input, p_h, new_h, u, s1, s2, s3, s4);
    k_colscore<<<(NN + 255) / 256, 256, 0, stream>>>(s1, s2, edge_col, row_i, iflag, ec, (unsigned int*)mseg);
    k_expsum<<<(NN + 255) / 256, 256, 0, stream>>>(ec, (const unsigned int*)mseg, row_i, iflag, ssum);
    k_norm<<<(NN + 255) / 256, 256, 0, stream>>>(ec, ssum, row_i, iflag, ecs);
    k_bhist<<<NE / 256, 256, 0, stream>>>(edge, iflag, bhist_p);
    k_bscan<<<1, 1024, 0, stream>>>(bhist_p, bstart, bcur_p);
    k_edge2<<<NE / 256, 256, 0, stream>>>(s3, s4, ecs, edge, row_resort, iflag, bcur_p, recs, out2);
    k_agg3<<<NB, 256, 0, stream>>>(h, recs, bstart, ersum, out0);
    k_att<<<NE / 256, 256, 0, stream>>>(edge, iflag, ersum, out2);
    k_edgecopy<<<2 * NE / 256, 256, 0, stream>>>(edge, iflag, out1);
}